// Round 11
// baseline (338.196 us; speedup 1.0000x reference)
//
#include <hip/hip_runtime.h>
#include <math.h>

#define NN 50000
#define EE 800000
#define HH 64
#define NBASIS 8
#define NLAYER 2
#define NGRAPH 64
#define NBLK1 49  // ceil(NN/1024)

using half2_t = decltype(__builtin_amdgcn_cvt_pkrtz(0.0f, 0.0f));
typedef _Float16 f16x8 __attribute__((ext_vector_type(8)));
typedef float f32x4 __attribute__((ext_vector_type(4)));

union U4H8 { uint4 u; f16x8 h; };

// r27: fast silu — v_rcp_f32 instead of the ~12-instr exact-division
// sequence. rel err ~1ulp, far below the f16 rounding this path tolerates.
__device__ __forceinline__ float silu_f(float v) {
    return v * __builtin_amdgcn_rcpf(1.0f + __expf(-v));
}

__device__ __forceinline__ unsigned pk2(float a, float b) {
    union { half2_t h; unsigned u; } x;
    x.h = __builtin_amdgcn_cvt_pkrtz(a, b);
    return x.u;
}

__device__ __forceinline__ half2_t u2h(unsigned u) {
    union { unsigned u; half2_t h; } x; x.u = u; return x.h;
}

// r28: degree count split out (the only prep piece scan depends on).
__global__ __launch_bounds__(256) void degcnt_k(
    const int* __restrict__ ecol, int* __restrict__ deg)
{
    int e = blockIdx.x * 256 + threadIdx.x;   // grid = EE/256 exactly
    atomicAdd(&deg[ecol[e]], 1);
}

// r26: scan2 fused via last-block ticket (bsum[63] is the ticket counter,
// zeroed by the widened memset). Classic threadfence-reduction pattern.
__global__ __launch_bounds__(1024) void scan1_k(
    const int* __restrict__ deg, int* __restrict__ cursor,
    int* __restrict__ bsum)
{
    __shared__ int wsum[16];
    __shared__ int lastFlag;
    int t = threadIdx.x, lane = t & 63, wave = t >> 6;
    int i = blockIdx.x * 1024 + t;
    int v = (i < NN) ? deg[i] : 0;
    int s = v;
#pragma unroll
    for (int off = 1; off < 64; off <<= 1) {
        int tv = __shfl_up(s, off, 64);
        if (lane >= off) s += tv;
    }
    if (lane == 63) wsum[wave] = s;
    __syncthreads();
    if (wave == 0) {
        int ws = (lane < 16) ? wsum[lane] : 0;
        int ss = ws;
#pragma unroll
        for (int off = 1; off < 16; off <<= 1) {
            int tv = __shfl_up(ss, off, 64);
            if (lane >= off) ss += tv;
        }
        if (lane < 16) wsum[lane] = ss - ws;
    }
    __syncthreads();
    int excl = wsum[wave] + s - v;
    if (i < NN) cursor[i] = excl;     // block-local exclusive scan
    if (t == 1023) {
        bsum[blockIdx.x] = excl + v;
        __threadfence();              // release: bsum store visible
        lastFlag = (atomicAdd(&bsum[63], 1) == NBLK1 - 1);
    }
    __syncthreads();
    if (lastFlag != 0 && wave == 0) { // last block: fused scan2
        __threadfence();              // acquire: see all bsum stores
        int vv = (lane < NBLK1) ? bsum[lane] : 0;
        int ss = vv;
#pragma unroll
        for (int off = 1; off < 64; off <<= 1) {
            int tv = __shfl_up(ss, off, 64);
            if (lane >= off) ss += tv;
        }
        if (lane < NBLK1) bsum[lane] = ss - vv;
    }
}

// r28: fused prep2 — scatter (blocks 0..3124) + embed gather (3125..9374)
// + weight prepack (9375..9486) + agg zero (9487..12611). Scatter is
// latency-bound on random 8B edgeS writes; co-residing it with the
// BW-bound gather/zero blocks fills those stalls (measured r28: 60.6 µs
// vs 54.5 scatter-alone + ~35 prep serialized).
// W2-fold (r19) unchanged: upd_w1 agg-half = msg_w2 @ upd_w1_agg; vbuf =
// b2-fold deg-bias.
__global__ __launch_bounds__(256) void prep2_k(
    const int* __restrict__ erow, const int* __restrict__ ecol,
    const float* __restrict__ pos,
    int* __restrict__ cursor, const int* __restrict__ bsum,
    uint2* __restrict__ edgeS,
    const int* __restrict__ z, const float* __restrict__ embed,
    unsigned* __restrict__ xh,
    const float* __restrict__ msg_w1, const float* __restrict__ msg_w2,
    const float* __restrict__ msg_b2,
    const float* __restrict__ upd_w1, const float* __restrict__ upd_w2,
    const float* __restrict__ eh_w1,
    unsigned* __restrict__ w1t, float* __restrict__ vbuf,
    unsigned* __restrict__ w1tu, unsigned* __restrict__ w2tu,
    unsigned* __restrict__ ehw1t,
    float4* __restrict__ agg4)
{
    int b = blockIdx.x;
    if (b < 3125) {                       // scatter: EE edges exactly
        int e = b * 256 + threadIdx.x;
        int c = ecol[e], r = erow[e];
        int slot = atomicAdd(&cursor[c], 1) + bsum[c >> 10];
        float dx = pos[3*r]   - pos[3*c];
        float dy = pos[3*r+1] - pos[3*c+1];
        float dz = pos[3*r+2] - pos[3*c+2];
        float d = sqrtf(dx*dx + dy*dy + dz*dz);
        uint2 v;
        v.x = ((unsigned)r << 16) | (unsigned)c;
        v.y = __float_as_uint(d);
        edgeS[slot] = v;
    } else if (b < 9375) {                // embed gather: NN*32 pairs
        int idx = (b - 3125) * 256 + threadIdx.x;  // < 1,600,000 always
        int n = idx >> 5;
        int p = idx & 31;
        const float2* er = (const float2*)(embed + ((size_t)z[n] << 6));
        float2 v = er[p];
        xh[idx] = pk2(v.x, v.y);
    } else if (b < 9487) {                // weight prepack, 28672 threads
        int idx = (b - 9375) * 256 + threadIdx.x;
        if (idx < 10240) {                    // msg w1t [l][f 64][kp 80]
            int l = idx / 5120, rem = idx % 5120;
            int f = rem / 80, kp = rem % 80;
            const float* w = msg_w1 + (size_t)l * 136 * 64;
            unsigned v = 0;
            if (kp < 68) v = pk2(w[(2*kp)*64 + f], w[(2*kp+1)*64 + f]);
            w1t[idx] = v;
        } else if (idx < 14336) {
            // retired: msg w2t no longer consumed (W2 folded into w1tu)
        } else if (idx < 22528) {             // upd w1tu [l][f 64][kp 64]
            int j = idx - 14336;
            int l = j / 4096, rem = j % 4096;
            int f = rem >> 6, kp = rem & 63;
            const float* w = upd_w1 + (size_t)l * 128 * 64;
            unsigned outv;
            if (kp < 32) {                    // x-half: passthrough
                outv = pk2(w[(2*kp)*64 + f], w[(2*kp+1)*64 + f]);
            } else {                          // agg-half: W2 @ W1u_agg
                const float* w2m = msg_w2 + (size_t)l * 64 * 64;
                int j0 = 2 * kp - 64;
                float v0 = 0.0f, v1 = 0.0f;
                for (int k = 0; k < 64; ++k) {
                    float wa = w[(64 + k) * 64 + f];
                    v0 += w2m[j0 * 64 + k]       * wa;
                    v1 += w2m[(j0 + 1) * 64 + k] * wa;
                }
                outv = pk2(v0, v1);
                if (kp == 63) {               // deg-bias vector vb
                    const float* b2m = msg_b2 + (size_t)l * 64;
                    float s = 0.0f;
                    for (int k = 0; k < 64; ++k)
                        s += b2m[k] * w[(64 + k) * 64 + f];
                    vbuf[l * 64 + f] = s;
                }
            }
            w1tu[j] = outv;
        } else if (idx < 26624) {             // upd w2tu [l][n 64][kp 32]
            int j = idx - 22528;
            int l = j / 2048, rem = j % 2048;
            int n = rem / 32, kp = rem % 32;
            const float* w = upd_w2 + (size_t)l * 64 * 64;
            w2tu[j] = pk2(w[(2*kp)*64 + n], w[(2*kp+1)*64 + n]);
        } else if (idx < 28672) {             // head ehw1t [f 64][kp 32]
            int j = idx - 26624;
            int f = j / 32, kp = j % 32;
            ehw1t[j] = pk2(eh_w1[(2*kp)*64 + f], eh_w1[(2*kp+1)*64 + f]);
        }
    } else {                              // agg zero: NN*16 float4
        int idx = (b - 9487) * 256 + threadIdx.x;
        if (idx < NN * 16) {
            float4 z4; z4.x = z4.y = z4.z = z4.w = 0.0f;
            agg4[idx] = z4;
        }
    }
}

// MFMA msg kernel. r29 (this round): 32-EDGE WINDOWS — the r25 post-mortem
// prescribed shedding live registers, not capping the allocator. Each wave
// now owns 32 sorted edges (block = 4 waves = 128 edges, grid EE/128):
// acc1[2][4] = 32 AGPR (was 64), bfr[2][2] = 16 (was 32), afrag/cn/rn
// halve. Peak live ~90 regs <= 102 -> __launch_bounds__(256,5) = 5
// waves/SIMD without spilling. Per-edge work identical (same MFMA/edge,
// same in-register segmented reduce with 8-edge chunks/lane + q-stitch);
// window-boundary flushes double (small atomic-write delta).
// Earlier history: r13 lockstep barrier; r18 early row gathers; r19 GEMM2
// folded into upd's w1tu; r24 transposed GEMM1 + in-register reduce;
// r27 fast-rcp silu.
__global__ __launch_bounds__(256, 5) void msg_k(
    const uint2* __restrict__ edgeS,
    const unsigned* __restrict__ xh,
    const unsigned* __restrict__ w1t, const float* __restrict__ b1,
    float* __restrict__ agg)
{
    __shared__ unsigned earrT[4][4 * 32];   // [wid][p*32 + e]
    __shared__ int ckey_s[4][32];

    const int wid  = threadIdx.x >> 6;
    const int lane = threadIdx.x & 63;
    const int l31 = lane & 31;
    const int q = lane >> 4, n15 = lane & 15;
    const size_t base = (size_t)blockIdx.x * 128 + wid * 32;

    uint2 ev = edgeS[base + l31];           // upper half duplicates lower
    int myrow = (int)(ev.x >> 16);
    int mykey = (int)(ev.x & 0xffffu);
    if (lane < 32) ckey_s[wid][lane] = mykey;

    // permuted edge slot: A-tile et, A-row n15 -> window offset oo0 + 4*et
    // (gives lane (q,*) the contiguous edges [8q, 8q+8) in its C regs)
    const int oo0 = 8 * (n15 >> 2) + (n15 & 3);

    int cn[2], rn[2];
#pragma unroll
    for (int et = 0; et < 2; ++et) {
        cn[et] = __shfl(mykey, oo0 + 4 * et, 64);
        rn[et] = __shfl(myrow, oo0 + 4 * et, 64);
    }

    // issue the random row gathers NOW; latency overlaps sinf phase
    U4H8 bfr[2][2];
#pragma unroll
    for (int et = 0; et < 2; ++et) {
        const uint4* rp = (const uint4*)(xh + ((size_t)rn[et] << 5));
        bfr[0][et].u = rp[q];
        bfr[1][et].u = rp[4 + q];
    }

    // ---- per-edge radial basis -> earrT (lanes 0-31 own edge l31) ----
    {
        float d = __uint_as_float(ev.y);
        float env = 0.0f;
        if (d < 5.0f) {
            float cv = __cosf(d * 0.31415926535897932f);  // pi/(2*CUTOFF)
            env = cv * cv;
        }
        float scale = (d > 0.0f) ? (env * __builtin_amdgcn_rcpf(d)) : env;
        float ea[NBASIS];
#pragma unroll
        for (int k = 0; k < NBASIS; ++k)
            ea[k] = __sinf((float)(k + 1) * 0.62831853071795865f * d) * scale;
        if (lane < 32) {
#pragma unroll
            for (int p = 0; p < 4; ++p)
                earrT[wid][p * 32 + lane] = pk2(ea[2*p], ea[2*p+1]);
        }
    }
    // boundary bitmask (window-local, lower 32 bits valid)
    int pkk = __shfl_up(mykey, 1, 64);
    unsigned long long bmask = __ballot(l31 > 0 && mykey != pkk);
    unsigned m32 = (unsigned)bmask;
    __syncthreads();   // lockstep + earrT/ckey visibility

    // ---- GEMM1 (transposed): D[edge][feat] ----
    f32x4 acc1[2][4];   // [et][ft]
#pragma unroll
    for (int ft = 0; ft < 4; ++ft) {
        float bv = b1[ft * 16 + n15];
        f32x4 binit; binit[0] = bv; binit[1] = bv; binit[2] = bv; binit[3] = bv;
        acc1[0][ft] = binit;
        acc1[1][ft] = binit;
    }
#pragma unroll
    for (int ks = 0; ks < 5; ++ks) {
        U4H8 afrag[2];
#pragma unroll
        for (int et = 0; et < 2; ++et) {
            if (ks == 4) {
                int eB = oo0 + 4 * et;
                unsigned e0 = earrT[wid][0 * 32 + eB];
                unsigned e1 = earrT[wid][1 * 32 + eB];
                unsigned e2 = earrT[wid][2 * 32 + eB];
                unsigned e3 = earrT[wid][3 * 32 + eB];
                afrag[et].u.x = (q == 0) ? e0 : 0u;
                afrag[et].u.y = (q == 0) ? e1 : 0u;
                afrag[et].u.z = (q == 0) ? e2 : 0u;
                afrag[et].u.w = (q == 0) ? e3 : 0u;
            } else if (ks < 2) {
                afrag[et].u = ((const uint4*)(xh + ((size_t)cn[et] << 5)))[ks * 4 + q];
            } else {
                afrag[et] = bfr[ks - 2][et];
            }
        }
#pragma unroll
        for (int ft = 0; ft < 4; ++ft) {
            U4H8 wf;
            wf.u = *(const uint4*)(w1t + (size_t)(ft * 16 + n15) * 80 + ks * 16 + q * 4);
#pragma unroll
            for (int et = 0; et < 2; ++et)
                acc1[et][ft] = __builtin_amdgcn_mfma_f32_16x16x32_f16(
                    afrag[et].h, wf.h, acc1[et][ft], 0, 0, 0);
        }
    }

    // ---- in-register segmented reduce over contiguous edges [8q, 8q+8).
    // value(i, ft) = silu(acc1[i>>2][ft][i&3]) = h[8q+i][16ft+n15].
    unsigned myb = (m32 >> (8 * q)) & 0xffu;
    const bool bstart = (myb & 1u) != 0;    // boundary AT chunk start (q0: 0)
    float run[4], hs[4];
#pragma unroll
    for (int ft = 0; ft < 4; ++ft) run[ft] = silu_f(acc1[0][ft][0]);
    bool seenb = false; int fb = 0;
#pragma unroll
    for (int i = 1; i < 8; ++i) {
        float vv[4];
#pragma unroll
        for (int ft = 0; ft < 4; ++ft) vv[ft] = silu_f(acc1[i >> 2][ft][i & 3]);
        if ((myb >> i) & 1u) {
            if (!seenb) {
                seenb = true; fb = i;
#pragma unroll
                for (int ft = 0; ft < 4; ++ft) hs[ft] = run[ft];
            } else {
                // interior segment: sole writer, plain store (64B coalesced)
                int kk = ckey_s[wid][8 * q + i - 1];
                float* dst = agg + ((size_t)kk << 6) + n15;
#pragma unroll
                for (int ft = 0; ft < 4; ++ft) dst[16 * ft] = run[ft];
            }
#pragma unroll
            for (int ft = 0; ft < 4; ++ft) run[ft] = vv[ft];
        } else {
#pragma unroll
            for (int ft = 0; ft < 4; ++ft) run[ft] += vv[ft];
        }
    }

    // ---- stitch across q-lanes: segmented inclusive scan of tails ----
    float ct[4];
#pragma unroll
    for (int ft = 0; ft < 4; ++ft) ct[ft] = run[ft];
    int brk = (seenb || bstart) ? 1 : 0;
    {
        float cp[4]; int bp;
#pragma unroll
        for (int ft = 0; ft < 4; ++ft) cp[ft] = __shfl_up(ct[ft], 16, 64);
        bp = __shfl_up(brk, 16, 64);
        if (q >= 1) {
            if (!brk) {
#pragma unroll
                for (int ft = 0; ft < 4; ++ft) ct[ft] += cp[ft];
            }
            brk |= bp;
        }
#pragma unroll
        for (int ft = 0; ft < 4; ++ft) cp[ft] = __shfl_up(ct[ft], 32, 64);
        bp = __shfl_up(brk, 32, 64);
        if (q >= 2) {
            if (!brk) {
#pragma unroll
                for (int ft = 0; ft < 4; ++ft) ct[ft] += cp[ft];
            }
            brk |= bp;
        }
    }
    float carry[4];
#pragma unroll
    for (int ft = 0; ft < 4; ++ft) carry[ft] = __shfl_up(ct[ft], 16, 64);
    // headflag: no boundary in window bits 1..8q-1 -> chain reaches edge 0
    const bool headflag = (q == 0) ||
        ((m32 & ((1u << (8 * q)) - 2u)) == 0u);

    if (q > 0 && bstart) {   // flush chain ending at edge 8q-1
        int kk = ckey_s[wid][8 * q - 1];
        float* dst = agg + ((size_t)kk << 6) + n15;
        if (headflag) {
#pragma unroll
            for (int ft = 0; ft < 4; ++ft) atomicAdd(dst + 16 * ft, carry[ft]);
        } else {
#pragma unroll
            for (int ft = 0; ft < 4; ++ft) dst[16 * ft] = carry[ft];
        }
    }
    if (seenb) {             // flush head segment [chunk start, fb-1]
        int kk = ckey_s[wid][8 * q + fb - 1];
        float* dst = agg + ((size_t)kk << 6) + n15;
        if (!bstart && q > 0) {
#pragma unroll
            for (int ft = 0; ft < 4; ++ft) hs[ft] += carry[ft];
        }
        if (headflag && !bstart) {
#pragma unroll
            for (int ft = 0; ft < 4; ++ft) atomicAdd(dst + 16 * ft, hs[ft]);
        } else {
#pragma unroll
            for (int ft = 0; ft < 4; ++ft) dst[16 * ft] = hs[ft];
        }
    }
    if (q == 3) {            // window tail, always atomic
        int kk = ckey_s[wid][31];
        float* dst = agg + ((size_t)kk << 6) + n15;
#pragma unroll
        for (int ft = 0; ft < 4; ++ft) atomicAdd(dst + 16 * ft, ct[ft]);
    }
}

// MFMA upd kernel: 16 nodes per wave, 256-thr blocks. Residual lives in xh
// (f16): epilogue reads old pair, adds, re-packs. Optional fused head and
// agg re-zero. r19+: w1t here carries the W2-folded agg-half; bias gains
// the per-node deg[n]*vb term (b2 of msg pushed through segment_sum).
__global__ __launch_bounds__(256) void upd_k(
    unsigned* __restrict__ xh,
    float* __restrict__ agg,
    const unsigned* __restrict__ w1t, const float* __restrict__ b1,
    const float* __restrict__ vb, const int* __restrict__ deg,
    const unsigned* __restrict__ w2t, const float* __restrict__ b2,
    const unsigned* __restrict__ ehw1t, const float* __restrict__ ehb1,
    const float* __restrict__ ehw2, const float* __restrict__ ehb2,
    const int* __restrict__ batch, float* __restrict__ energy,
    int do_zero, int do_head)
{
    __shared__ unsigned MU[4][16 * 33];   // per-wave f16-pair staging
    __shared__ float esum[NGRAPH];

    const int tid = threadIdx.x;
    const int wid = tid >> 6;
    const int lane = tid & 63;
    const int q = lane >> 4, n15 = lane & 15;
    const int base16 = blockIdx.x * 64 + wid * 16;   // wave's first node

    if (do_head) {
        if (tid < NGRAPH) esum[tid] = 0.0f;
        __syncthreads();
    }

    int nodeB = base16 + n15;
    int ncB = (nodeB < NN) ? nodeB : (NN - 1);

    // ---- GEMM1: H^T = W1T @ u_in^T, K=128, single node tile ----
    float degf = (float)deg[ncB];
    f32x4 acc1[4];
#pragma unroll
    for (int mt = 0; mt < 4; ++mt) {
        f32x4 bi = *(const f32x4*)(b1 + mt * 16 + q * 4);
        f32x4 vv = *(const f32x4*)(vb + mt * 16 + q * 4);
#pragma unroll
        for (int r = 0; r < 4; ++r) bi[r] = fmaf(degf, vv[r], bi[r]);
        acc1[mt] = bi;
    }
#pragma unroll
    for (int ks = 0; ks < 4; ++ks) {
        U4H8 bfk;
        if (ks < 2) {
            bfk.u = ((const uint4*)(xh + ((size_t)ncB << 5)))[ks * 4 + q];
        } else {
            const float4* ap = (const float4*)(agg + ((size_t)ncB << 6));
            int o = (ks - 2) * 8 + 2 * q;
            float4 a0 = ap[o], a1 = ap[o + 1];
            bfk.u.x = pk2(a0.x, a0.y); bfk.u.y = pk2(a0.z, a0.w);
            bfk.u.z = pk2(a1.x, a1.y); bfk.u.w = pk2(a1.z, a1.w);
        }
#pragma unroll
        for (int mt = 0; mt < 4; ++mt) {
            U4H8 af;
            af.u = *(const uint4*)(w1t + (size_t)(mt * 16 + n15) * 64 + ks * 16 + q * 4);
            acc1[mt] = __builtin_amdgcn_mfma_f32_16x16x32_f16(
                af.h, bfk.h, acc1[mt], 0, 0, 0);
        }
    }

    // ---- silu + pack ----
    unsigned psrc[4][2];
#pragma unroll
    for (int mt = 0; mt < 4; ++mt) {
        psrc[mt][0] = pk2(silu_f(acc1[mt][0]), silu_f(acc1[mt][1]));
        psrc[mt][1] = pk2(silu_f(acc1[mt][2]), silu_f(acc1[mt][3]));
    }

    // ---- GEMM2: out = P @ W2, K=64 ----
    f32x4 acc2[4];
#pragma unroll
    for (int nt = 0; nt < 4; ++nt) {
        float b2v = b2[nt * 16 + n15];
        acc2[nt][0] = b2v; acc2[nt][1] = b2v; acc2[nt][2] = b2v; acc2[nt][3] = b2v;
    }
#pragma unroll
    for (int ks2 = 0; ks2 < 2; ++ks2) {
        unsigned tmp[4];
#pragma unroll
        for (int jr = 0; jr < 4; ++jr) {
            int srcl = (2 * (q & 1) + (jr >> 1)) * 16 + n15;
            unsigned v0 = (unsigned)__shfl((int)psrc[2 * ks2][jr & 1], srcl, 64);
            unsigned v1 = (unsigned)__shfl((int)psrc[2 * ks2 + 1][jr & 1], srcl, 64);
            tmp[jr] = (q >> 1) ? v1 : v0;
        }
        U4H8 pf;
        pf.u.x = tmp[0]; pf.u.y = tmp[1]; pf.u.z = tmp[2]; pf.u.w = tmp[3];
#pragma unroll
        for (int nt = 0; nt < 4; ++nt) {
            U4H8 wb;
            wb.u = *(const uint4*)(w2t + (size_t)(nt * 16 + n15) * 32 + ks2 * 16 + q * 4);
            acc2[nt] = __builtin_amdgcn_mfma_f32_16x16x32_f16(
                pf.h, wb.h, acc2[nt], 0, 0, 0);
        }
    }

    // ---- epilogue: xh += out (f16 residual), pairs via shfl_xor ----
    // acc2[nt][r] = out[node = base16+4q+r][feat = 16nt+n15]
#pragma unroll
    for (int nt = 0; nt < 4; ++nt) {
#pragma unroll
        for (int r = 0; r < 4; ++r) {
            int node = base16 + 4 * q + r;
            float vnew = 0.0f;
            if (node < NN) {
                unsigned pu = xh[((size_t)node << 5) + (unsigned)((nt * 16 + n15) >> 1)];
                half2_t hp = u2h(pu);
                float vold = (n15 & 1) ? (float)hp[1] : (float)hp[0];
                vnew = vold + acc2[nt][r];
            }
            float vpart = __shfl_xor(vnew, 1, 64);
            if ((n15 & 1) == 0) {
                unsigned pv = pk2(vnew, vpart);
                int pidx = nt * 8 + (n15 >> 1);
                MU[wid][(4 * q + r) * 33 + pidx] = pv;
                if (node < NN) xh[((size_t)node << 5) + pidx] = pv;
            }
        }
    }

    if (do_zero) {   // re-zero exactly the agg chunks this lane read
        if (nodeB < NN) {
            float4 z4; z4.x = z4.y = z4.z = z4.w = 0.0f;
            float4* ap = (float4*)(agg + ((size_t)nodeB << 6));
            ap[2*q] = z4; ap[2*q + 1] = z4;
            ap[8 + 2*q] = z4; ap[8 + 2*q + 1] = z4;
        }
    }

    if (do_head) {
        __syncthreads();   // MU visibility
        f32x4 acch[4];
#pragma unroll
        for (int mt = 0; mt < 4; ++mt)
            acch[mt] = *(const f32x4*)(ehb1 + mt * 16 + q * 4);
#pragma unroll
        for (int ks = 0; ks < 2; ++ks) {
            U4H8 bfk;
            bfk.u.x = MU[wid][n15 * 33 + ks * 16 + 4 * q + 0];
            bfk.u.y = MU[wid][n15 * 33 + ks * 16 + 4 * q + 1];
            bfk.u.z = MU[wid][n15 * 33 + ks * 16 + 4 * q + 2];
            bfk.u.w = MU[wid][n15 * 33 + ks * 16 + 4 * q + 3];
#pragma unroll
            for (int mt = 0; mt < 4; ++mt) {
                U4H8 af;
                af.u = *(const uint4*)(ehw1t + (size_t)(mt * 16 + n15) * 32 + ks * 16 + q * 4);
                acch[mt] = __builtin_amdgcn_mfma_f32_16x16x32_f16(
                    af.h, bfk.h, acch[mt], 0, 0, 0);
            }
        }
        f32x4 wv[4];
#pragma unroll
        for (int mt = 0; mt < 4; ++mt)
            wv[mt] = *(const f32x4*)(ehw2 + mt * 16 + q * 4);
        float e = 0.0f;
#pragma unroll
        for (int mt = 0; mt < 4; ++mt)
#pragma unroll
            for (int r = 0; r < 4; ++r)
                e = fmaf(silu_f(acch[mt][r]), wv[mt][r], e);
        e += __shfl_xor(e, 16, 64);
        e += __shfl_xor(e, 32, 64);
        if (q == 0) {
            int node = base16 + n15;
            if (node < NN) atomicAdd(&esum[batch[node]], e + ehb2[0]);
        }
        __syncthreads();
        if (tid < NGRAPH) {
            float v = esum[tid];
            if (v != 0.0f) atomicAdd(energy + tid, v);
        }
    }
}

extern "C" void kernel_launch(void* const* d_in, const int* in_sizes, int n_in,
                              void* d_out, int out_size, void* d_ws, size_t ws_size,
                              hipStream_t stream) {
    const int*   z       = (const int*)  d_in[0];
    const float* pos     = (const float*)d_in[1];
    const int*   eidx    = (const int*)  d_in[2];
    const int*   batch   = (const int*)  d_in[3];
    const float* embed   = (const float*)d_in[4];
    const float* msg_w1  = (const float*)d_in[5];
    const float* msg_b1  = (const float*)d_in[6];
    const float* msg_w2  = (const float*)d_in[7];
    const float* msg_b2  = (const float*)d_in[8];
    const float* upd_w1  = (const float*)d_in[9];
    const float* upd_b1  = (const float*)d_in[10];
    const float* upd_w2  = (const float*)d_in[11];
    const float* upd_b2  = (const float*)d_in[12];
    const float* eh_w1   = (const float*)d_in[13];
    const float* eh_b1   = (const float*)d_in[14];
    const float* eh_w2   = (const float*)d_in[15];
    const float* eh_b2   = (const float*)d_in[16];

    const int* erow = eidx;
    const int* ecol = eidx + EE;

    // ws layout (4-byte units); edgeS offset is 8B-aligned
    float*    agg    = (float*)d_ws;                      // NN*64
    unsigned* xh     = (unsigned*)(agg + (size_t)NN * HH);// NN*32
    int*      deg    = (int*)(xh + (size_t)NN * 32);      // NN
    int*      cursor = deg + NN;                          // NN
    int*      bsum   = cursor + NN;                       // 64 (bsum[63] = ticket)
    uint2*    edgeS  = (uint2*)(bsum + 64);               // EE uint2 (8B)
    unsigned* w1t    = (unsigned*)(edgeS + EE);           // NL*64*80
    unsigned* w2t    = w1t + NLAYER * 64 * 80;            // NL*64*32 (retired; hosts vbuf)
    unsigned* w1tu   = w2t + NLAYER * 64 * 32;            // NL*64*64
    unsigned* w2tu   = w1tu + NLAYER * 64 * 64;           // NL*64*32
    unsigned* ehw1t  = w2tu + NLAYER * 64 * 32;           // 64*32
    float*    vbuf   = (float*)w2t;                       // NL*64 (in w2t slot)
    float*    energy = (float*)d_out;

    (void)hipMemsetAsync(energy, 0, NGRAPH * sizeof(float), stream);
    // zero deg + cursor + bsum (incl. bsum[63] ticket) in one call
    (void)hipMemsetAsync(deg, 0, (2 * NN + 64) * sizeof(int), stream);

    // r28 pipeline: degcount -> scan -> fused{scatter | gather | prepack |
    // aggzero} -> layers.
    degcnt_k<<<EE / 256, 256, 0, stream>>>(ecol, deg);
    scan1_k<<<NBLK1, 1024, 0, stream>>>(deg, cursor, bsum);  // scan2 fused
    prep2_k<<<12612, 256, 0, stream>>>(
        erow, ecol, pos, cursor, bsum, edgeS,
        z, embed, xh,
        msg_w1, msg_w2, msg_b2, upd_w1, upd_w2, eh_w1,
        w1t, vbuf, w1tu, w2tu, ehw1t,
        (float4*)agg);

    for (int l = 0; l < NLAYER; ++l) {
        msg_k<<<EE / 128, 256, 0, stream>>>(   // r29: 32-edge windows
            edgeS, xh,
            w1t + (size_t)l * 64 * 80,
            msg_b1 + (size_t)l * HH,
            agg);
        upd_k<<<(NN + 63) / 64, 256, 0, stream>>>(
            xh, agg,
            w1tu + (size_t)l * 64 * 64,
            upd_b1 + (size_t)l * HH,
            vbuf + (size_t)l * 64,
            deg,
            w2tu + (size_t)l * 64 * 32,
            upd_b2 + (size_t)l * HH,
            ehw1t, eh_b1, eh_w2, eh_b2, batch, energy,
            (l == 0) ? 1 : 0,            // re-zero agg for next layer
            (l == NLAYER - 1) ? 1 : 0);  // fused head on last layer
    }
}

// Round 12
// 328.940 us; speedup vs baseline: 1.0281x; 1.0281x over previous
//
#include <hip/hip_runtime.h>
#include <math.h>

#define NN 50000
#define EE 800000
#define HH 64
#define NBASIS 8
#define NLAYER 2
#define NGRAPH 64
#define NBLK1 49  // ceil(NN/1024)

using half2_t = decltype(__builtin_amdgcn_cvt_pkrtz(0.0f, 0.0f));
typedef _Float16 f16x8 __attribute__((ext_vector_type(8)));
typedef float f32x4 __attribute__((ext_vector_type(4)));

union U4H8 { uint4 u; f16x8 h; };

// r27: fast silu — v_rcp_f32 instead of the ~12-instr exact-division
// sequence. rel err ~1ulp, far below the f16 rounding this path tolerates.
__device__ __forceinline__ float silu_f(float v) {
    return v * __builtin_amdgcn_rcpf(1.0f + __expf(-v));
}

__device__ __forceinline__ unsigned pk2(float a, float b) {
    union { half2_t h; unsigned u; } x;
    x.h = __builtin_amdgcn_cvt_pkrtz(a, b);
    return x.u;
}

__device__ __forceinline__ half2_t u2h(unsigned u) {
    union { unsigned u; half2_t h; } x; x.u = u; return x.h;
}

// r28: degree count split out (the only prep piece scan depends on).
__global__ __launch_bounds__(256) void degcnt_k(
    const int* __restrict__ ecol, int* __restrict__ deg)
{
    int e = blockIdx.x * 256 + threadIdx.x;   // grid = EE/256 exactly
    atomicAdd(&deg[ecol[e]], 1);
}

// r26: scan2 fused via last-block ticket (bsum[63] is the ticket counter,
// zeroed by the widened memset). Classic threadfence-reduction pattern.
__global__ __launch_bounds__(1024) void scan1_k(
    const int* __restrict__ deg, int* __restrict__ cursor,
    int* __restrict__ bsum)
{
    __shared__ int wsum[16];
    __shared__ int lastFlag;
    int t = threadIdx.x, lane = t & 63, wave = t >> 6;
    int i = blockIdx.x * 1024 + t;
    int v = (i < NN) ? deg[i] : 0;
    int s = v;
#pragma unroll
    for (int off = 1; off < 64; off <<= 1) {
        int tv = __shfl_up(s, off, 64);
        if (lane >= off) s += tv;
    }
    if (lane == 63) wsum[wave] = s;
    __syncthreads();
    if (wave == 0) {
        int ws = (lane < 16) ? wsum[lane] : 0;
        int ss = ws;
#pragma unroll
        for (int off = 1; off < 16; off <<= 1) {
            int tv = __shfl_up(ss, off, 64);
            if (lane >= off) ss += tv;
        }
        if (lane < 16) wsum[lane] = ss - ws;
    }
    __syncthreads();
    int excl = wsum[wave] + s - v;
    if (i < NN) cursor[i] = excl;     // block-local exclusive scan
    if (t == 1023) {
        bsum[blockIdx.x] = excl + v;
        __threadfence();              // release: bsum store visible
        lastFlag = (atomicAdd(&bsum[63], 1) == NBLK1 - 1);
    }
    __syncthreads();
    if (lastFlag != 0 && wave == 0) { // last block: fused scan2
        __threadfence();              // acquire: see all bsum stores
        int vv = (lane < NBLK1) ? bsum[lane] : 0;
        int ss = vv;
#pragma unroll
        for (int off = 1; off < 64; off <<= 1) {
            int tv = __shfl_up(ss, off, 64);
            if (lane >= off) ss += tv;
        }
        if (lane < NBLK1) bsum[lane] = ss - vv;
    }
}

// r28: fused prep2 — scatter (blocks 0..3124) + embed gather (3125..9374)
// + weight prepack (9375..9486) + agg zero (9487..12611). Scatter is
// latency-bound on random 8B edgeS writes (cross-XCD false-sharing forces
// ~full-line write traffic); co-residing it with the BW-bound gather/zero
// blocks fills those stalls (measured r28: 60.6 µs vs 54.5 + ~35 serial).
// W2-fold (r19) unchanged: upd_w1 agg-half = msg_w2 @ upd_w1_agg; vbuf =
// b2-fold deg-bias.
__global__ __launch_bounds__(256) void prep2_k(
    const int* __restrict__ erow, const int* __restrict__ ecol,
    const float* __restrict__ pos,
    int* __restrict__ cursor, const int* __restrict__ bsum,
    uint2* __restrict__ edgeS,
    const int* __restrict__ z, const float* __restrict__ embed,
    unsigned* __restrict__ xh,
    const float* __restrict__ msg_w1, const float* __restrict__ msg_w2,
    const float* __restrict__ msg_b2,
    const float* __restrict__ upd_w1, const float* __restrict__ upd_w2,
    const float* __restrict__ eh_w1,
    unsigned* __restrict__ w1t, float* __restrict__ vbuf,
    unsigned* __restrict__ w1tu, unsigned* __restrict__ w2tu,
    unsigned* __restrict__ ehw1t,
    float4* __restrict__ agg4)
{
    int b = blockIdx.x;
    if (b < 3125) {                       // scatter: EE edges exactly
        int e = b * 256 + threadIdx.x;
        int c = ecol[e], r = erow[e];
        int slot = atomicAdd(&cursor[c], 1) + bsum[c >> 10];
        float dx = pos[3*r]   - pos[3*c];
        float dy = pos[3*r+1] - pos[3*c+1];
        float dz = pos[3*r+2] - pos[3*c+2];
        float d = sqrtf(dx*dx + dy*dy + dz*dz);
        uint2 v;
        v.x = ((unsigned)r << 16) | (unsigned)c;
        v.y = __float_as_uint(d);
        edgeS[slot] = v;
    } else if (b < 9375) {                // embed gather: NN*32 pairs
        int idx = (b - 3125) * 256 + threadIdx.x;  // < 1,600,000 always
        int n = idx >> 5;
        int p = idx & 31;
        const float2* er = (const float2*)(embed + ((size_t)z[n] << 6));
        float2 v = er[p];
        xh[idx] = pk2(v.x, v.y);
    } else if (b < 9487) {                // weight prepack, 28672 threads
        int idx = (b - 9375) * 256 + threadIdx.x;
        if (idx < 10240) {                    // msg w1t [l][f 64][kp 80]
            int l = idx / 5120, rem = idx % 5120;
            int f = rem / 80, kp = rem % 80;
            const float* w = msg_w1 + (size_t)l * 136 * 64;
            unsigned v = 0;
            if (kp < 68) v = pk2(w[(2*kp)*64 + f], w[(2*kp+1)*64 + f]);
            w1t[idx] = v;
        } else if (idx < 14336) {
            // retired: msg w2t no longer consumed (W2 folded into w1tu)
        } else if (idx < 22528) {             // upd w1tu [l][f 64][kp 64]
            int j = idx - 14336;
            int l = j / 4096, rem = j % 4096;
            int f = rem >> 6, kp = rem & 63;
            const float* w = upd_w1 + (size_t)l * 128 * 64;
            unsigned outv;
            if (kp < 32) {                    // x-half: passthrough
                outv = pk2(w[(2*kp)*64 + f], w[(2*kp+1)*64 + f]);
            } else {                          // agg-half: W2 @ W1u_agg
                const float* w2m = msg_w2 + (size_t)l * 64 * 64;
                int j0 = 2 * kp - 64;
                float v0 = 0.0f, v1 = 0.0f;
                for (int k = 0; k < 64; ++k) {
                    float wa = w[(64 + k) * 64 + f];
                    v0 += w2m[j0 * 64 + k]       * wa;
                    v1 += w2m[(j0 + 1) * 64 + k] * wa;
                }
                outv = pk2(v0, v1);
                if (kp == 63) {               // deg-bias vector vb
                    const float* b2m = msg_b2 + (size_t)l * 64;
                    float s = 0.0f;
                    for (int k = 0; k < 64; ++k)
                        s += b2m[k] * w[(64 + k) * 64 + f];
                    vbuf[l * 64 + f] = s;
                }
            }
            w1tu[j] = outv;
        } else if (idx < 26624) {             // upd w2tu [l][n 64][kp 32]
            int j = idx - 22528;
            int l = j / 2048, rem = j % 2048;
            int n = rem / 32, kp = rem % 32;
            const float* w = upd_w2 + (size_t)l * 64 * 64;
            w2tu[j] = pk2(w[(2*kp)*64 + n], w[(2*kp+1)*64 + n]);
        } else if (idx < 28672) {             // head ehw1t [f 64][kp 32]
            int j = idx - 26624;
            int f = j / 32, kp = j % 32;
            ehw1t[j] = pk2(eh_w1[(2*kp)*64 + f], eh_w1[(2*kp+1)*64 + f]);
        }
    } else {                              // agg zero: NN*16 float4
        int idx = (b - 9487) * 256 + threadIdx.x;
        if (idx < NN * 16) {
            float4 z4; z4.x = z4.y = z4.z = z4.w = 0.0f;
            agg4[idx] = z4;
        }
    }
}

// MFMA msg kernel: 256-thread blocks = 4 private waves x 64 sorted edges.
// r13: one barrier for wave lockstep. r18: row gathers before the
// transcendental block. r19: GEMM2 folded into upd's w1tu. r24: transposed
// GEMM1 (C = [edge][feat]) + in-register segmented reduce. r27: fast-rcp
// silu. PROVEN 53.3 µs at (256,4), 64-edge windows.
// OCCUPANCY LINE CLOSED (r25+r29): capping regs at (256,5) spills (live
// set ~128); shrinking to 32-edge windows doubles per-edge fixed costs
// (weight loads, rbf redundancy, stitch) and is net -13%. The 64-edge
// window at 4 waves/SIMD is the local optimum of this structure.
__global__ __launch_bounds__(256, 4) void msg_k(
    const uint2* __restrict__ edgeS,
    const unsigned* __restrict__ xh,
    const unsigned* __restrict__ w1t, const float* __restrict__ b1,
    float* __restrict__ agg)
{
    __shared__ unsigned earrT[4][4 * 64];   // [wid][p*64 + lane]
    __shared__ int ckey_s[4][64];

    const int wid  = threadIdx.x >> 6;
    const int lane = threadIdx.x & 63;
    const int q = lane >> 4, n15 = lane & 15;
    const size_t base = (size_t)blockIdx.x * 256 + wid * 64;

    uint2 ev = edgeS[base + lane];
    int myrow = (int)(ev.x >> 16);
    int mykey = (int)(ev.x & 0xffffu);
    ckey_s[wid][lane] = mykey;

    // permuted edge slot: A-tile et, A-row n15 -> sorted offset oo0 + 4*et
    // (gives lane (q,*) the contiguous edges [16q, 16q+15] in its C regs)
    const int oo0 = 16 * (n15 >> 2) + (n15 & 3);

    int cn[4], rn[4];
#pragma unroll
    for (int et = 0; et < 4; ++et) {
        cn[et] = __shfl(mykey, oo0 + 4 * et, 64);
        rn[et] = __shfl(myrow, oo0 + 4 * et, 64);
    }

    // issue the random row gathers NOW; latency overlaps sinf phase
    U4H8 bfr[2][4];
#pragma unroll
    for (int et = 0; et < 4; ++et) {
        const uint4* rp = (const uint4*)(xh + ((size_t)rn[et] << 5));
        bfr[0][et].u = rp[q];
        bfr[1][et].u = rp[4 + q];
    }

    // ---- per-edge radial basis -> earrT (own edge at own position) ----
    {
        float d = __uint_as_float(ev.y);
        float env = 0.0f;
        if (d < 5.0f) {
            float cv = __cosf(d * 0.31415926535897932f);  // pi/(2*CUTOFF)
            env = cv * cv;
        }
        float scale = (d > 0.0f) ? (env * __builtin_amdgcn_rcpf(d)) : env;
        float ea[NBASIS];
#pragma unroll
        for (int k = 0; k < NBASIS; ++k)
            ea[k] = __sinf((float)(k + 1) * 0.62831853071795865f * d) * scale;
#pragma unroll
        for (int p = 0; p < 4; ++p)
            earrT[wid][p * 64 + lane] = pk2(ea[2*p], ea[2*p+1]);
    }
    // boundary bitmask: bit L set iff key[L] != key[L-1]
    int pkk = __shfl_up(mykey, 1, 64);
    unsigned long long bmask = __ballot(lane > 0 && mykey != pkk);
    __syncthreads();   // lockstep + earrT/ckey visibility

    // ---- GEMM1 (transposed): D[edge][feat] ----
    f32x4 acc1[4][4];   // [et][ft]
#pragma unroll
    for (int ft = 0; ft < 4; ++ft) {
        float bv = b1[ft * 16 + n15];
        f32x4 binit; binit[0] = bv; binit[1] = bv; binit[2] = bv; binit[3] = bv;
#pragma unroll
        for (int et = 0; et < 4; ++et) acc1[et][ft] = binit;
    }
#pragma unroll
    for (int ks = 0; ks < 5; ++ks) {
        U4H8 afrag[4];
#pragma unroll
        for (int et = 0; et < 4; ++et) {
            if (ks == 4) {
                int eB = oo0 + 4 * et;
                unsigned e0 = earrT[wid][0 * 64 + eB];
                unsigned e1 = earrT[wid][1 * 64 + eB];
                unsigned e2 = earrT[wid][2 * 64 + eB];
                unsigned e3 = earrT[wid][3 * 64 + eB];
                afrag[et].u.x = (q == 0) ? e0 : 0u;
                afrag[et].u.y = (q == 0) ? e1 : 0u;
                afrag[et].u.z = (q == 0) ? e2 : 0u;
                afrag[et].u.w = (q == 0) ? e3 : 0u;
            } else if (ks < 2) {
                afrag[et].u = ((const uint4*)(xh + ((size_t)cn[et] << 5)))[ks * 4 + q];
            } else {
                afrag[et] = bfr[ks - 2][et];
            }
        }
#pragma unroll
        for (int ft = 0; ft < 4; ++ft) {
            U4H8 wf;
            wf.u = *(const uint4*)(w1t + (size_t)(ft * 16 + n15) * 80 + ks * 16 + q * 4);
#pragma unroll
            for (int et = 0; et < 4; ++et)
                acc1[et][ft] = __builtin_amdgcn_mfma_f32_16x16x32_f16(
                    afrag[et].h, wf.h, acc1[et][ft], 0, 0, 0);
        }
    }

    // ---- in-register segmented reduce over contiguous edges [16q,16q+15].
    // value(i, ft) = silu(acc1[i>>2][ft][i&3]) = h[16q+i][16ft+n15].
    unsigned myb = (unsigned)((bmask >> (16 * q)) & 0xffffull);
    const bool bstart = (myb & 1u) != 0;    // boundary AT block start (q0: 0)
    float run[4], hs[4];
#pragma unroll
    for (int ft = 0; ft < 4; ++ft) run[ft] = silu_f(acc1[0][ft][0]);
    bool seenb = false; int fb = 0;
#pragma unroll
    for (int i = 1; i < 16; ++i) {
        float vv[4];
#pragma unroll
        for (int ft = 0; ft < 4; ++ft) vv[ft] = silu_f(acc1[i >> 2][ft][i & 3]);
        if ((myb >> i) & 1u) {
            if (!seenb) {
                seenb = true; fb = i;
#pragma unroll
                for (int ft = 0; ft < 4; ++ft) hs[ft] = run[ft];
            } else {
                // interior segment: sole writer, plain store (64B coalesced)
                int kk = ckey_s[wid][16 * q + i - 1];
                float* dst = agg + ((size_t)kk << 6) + n15;
#pragma unroll
                for (int ft = 0; ft < 4; ++ft) dst[16 * ft] = run[ft];
            }
#pragma unroll
            for (int ft = 0; ft < 4; ++ft) run[ft] = vv[ft];
        } else {
#pragma unroll
            for (int ft = 0; ft < 4; ++ft) run[ft] += vv[ft];
        }
    }

    // ---- stitch across q-lanes: segmented inclusive scan of tails ----
    float ct[4];
#pragma unroll
    for (int ft = 0; ft < 4; ++ft) ct[ft] = run[ft];
    int brk = (seenb || bstart) ? 1 : 0;
    {
        float cp[4]; int bp;
#pragma unroll
        for (int ft = 0; ft < 4; ++ft) cp[ft] = __shfl_up(ct[ft], 16, 64);
        bp = __shfl_up(brk, 16, 64);
        if (q >= 1) {
            if (!brk) {
#pragma unroll
                for (int ft = 0; ft < 4; ++ft) ct[ft] += cp[ft];
            }
            brk |= bp;
        }
#pragma unroll
        for (int ft = 0; ft < 4; ++ft) cp[ft] = __shfl_up(ct[ft], 32, 64);
        bp = __shfl_up(brk, 32, 64);
        if (q >= 2) {
            if (!brk) {
#pragma unroll
                for (int ft = 0; ft < 4; ++ft) ct[ft] += cp[ft];
            }
            brk |= bp;
        }
    }
    float carry[4];
#pragma unroll
    for (int ft = 0; ft < 4; ++ft) carry[ft] = __shfl_up(ct[ft], 16, 64);
    // headflag: no boundary in window bits 1..16q-1 -> chain reaches edge 0
    const bool headflag = (q == 0) ||
        ((bmask & (((unsigned long long)1 << (16 * q)) - 2)) == 0ull);

    if (q > 0 && bstart) {   // flush chain ending at edge 16q-1
        int kk = ckey_s[wid][16 * q - 1];
        float* dst = agg + ((size_t)kk << 6) + n15;
        if (headflag) {
#pragma unroll
            for (int ft = 0; ft < 4; ++ft) atomicAdd(dst + 16 * ft, carry[ft]);
        } else {
#pragma unroll
            for (int ft = 0; ft < 4; ++ft) dst[16 * ft] = carry[ft];
        }
    }
    if (seenb) {             // flush head segment [block start, fb-1]
        int kk = ckey_s[wid][16 * q + fb - 1];
        float* dst = agg + ((size_t)kk << 6) + n15;
        if (!bstart && q > 0) {
#pragma unroll
            for (int ft = 0; ft < 4; ++ft) hs[ft] += carry[ft];
        }
        if (headflag && !bstart) {
#pragma unroll
            for (int ft = 0; ft < 4; ++ft) atomicAdd(dst + 16 * ft, hs[ft]);
        } else {
#pragma unroll
            for (int ft = 0; ft < 4; ++ft) dst[16 * ft] = hs[ft];
        }
    }
    if (q == 3) {            // window tail, always atomic
        int kk = ckey_s[wid][63];
        float* dst = agg + ((size_t)kk << 6) + n15;
#pragma unroll
        for (int ft = 0; ft < 4; ++ft) atomicAdd(dst + 16 * ft, ct[ft]);
    }
}

// MFMA upd kernel: 16 nodes per wave, 256-thr blocks. Residual lives in xh
// (f16): epilogue reads old pair, adds, re-packs. Optional fused head and
// agg re-zero. r19+: w1t here carries the W2-folded agg-half; bias gains
// the per-node deg[n]*vb term (b2 of msg pushed through segment_sum).
__global__ __launch_bounds__(256) void upd_k(
    unsigned* __restrict__ xh,
    float* __restrict__ agg,
    const unsigned* __restrict__ w1t, const float* __restrict__ b1,
    const float* __restrict__ vb, const int* __restrict__ deg,
    const unsigned* __restrict__ w2t, const float* __restrict__ b2,
    const unsigned* __restrict__ ehw1t, const float* __restrict__ ehb1,
    const float* __restrict__ ehw2, const float* __restrict__ ehb2,
    const int* __restrict__ batch, float* __restrict__ energy,
    int do_zero, int do_head)
{
    __shared__ unsigned MU[4][16 * 33];   // per-wave f16-pair staging
    __shared__ float esum[NGRAPH];

    const int tid = threadIdx.x;
    const int wid = tid >> 6;
    const int lane = tid & 63;
    const int q = lane >> 4, n15 = lane & 15;
    const int base16 = blockIdx.x * 64 + wid * 16;   // wave's first node

    if (do_head) {
        if (tid < NGRAPH) esum[tid] = 0.0f;
        __syncthreads();
    }

    int nodeB = base16 + n15;
    int ncB = (nodeB < NN) ? nodeB : (NN - 1);

    // ---- GEMM1: H^T = W1T @ u_in^T, K=128, single node tile ----
    float degf = (float)deg[ncB];
    f32x4 acc1[4];
#pragma unroll
    for (int mt = 0; mt < 4; ++mt) {
        f32x4 bi = *(const f32x4*)(b1 + mt * 16 + q * 4);
        f32x4 vv = *(const f32x4*)(vb + mt * 16 + q * 4);
#pragma unroll
        for (int r = 0; r < 4; ++r) bi[r] = fmaf(degf, vv[r], bi[r]);
        acc1[mt] = bi;
    }
#pragma unroll
    for (int ks = 0; ks < 4; ++ks) {
        U4H8 bfk;
        if (ks < 2) {
            bfk.u = ((const uint4*)(xh + ((size_t)ncB << 5)))[ks * 4 + q];
        } else {
            const float4* ap = (const float4*)(agg + ((size_t)ncB << 6));
            int o = (ks - 2) * 8 + 2 * q;
            float4 a0 = ap[o], a1 = ap[o + 1];
            bfk.u.x = pk2(a0.x, a0.y); bfk.u.y = pk2(a0.z, a0.w);
            bfk.u.z = pk2(a1.x, a1.y); bfk.u.w = pk2(a1.z, a1.w);
        }
#pragma unroll
        for (int mt = 0; mt < 4; ++mt) {
            U4H8 af;
            af.u = *(const uint4*)(w1t + (size_t)(mt * 16 + n15) * 64 + ks * 16 + q * 4);
            acc1[mt] = __builtin_amdgcn_mfma_f32_16x16x32_f16(
                af.h, bfk.h, acc1[mt], 0, 0, 0);
        }
    }

    // ---- silu + pack ----
    unsigned psrc[4][2];
#pragma unroll
    for (int mt = 0; mt < 4; ++mt) {
        psrc[mt][0] = pk2(silu_f(acc1[mt][0]), silu_f(acc1[mt][1]));
        psrc[mt][1] = pk2(silu_f(acc1[mt][2]), silu_f(acc1[mt][3]));
    }

    // ---- GEMM2: out = P @ W2, K=64 ----
    f32x4 acc2[4];
#pragma unroll
    for (int nt = 0; nt < 4; ++nt) {
        float b2v = b2[nt * 16 + n15];
        acc2[nt][0] = b2v; acc2[nt][1] = b2v; acc2[nt][2] = b2v; acc2[nt][3] = b2v;
    }
#pragma unroll
    for (int ks2 = 0; ks2 < 2; ++ks2) {
        unsigned tmp[4];
#pragma unroll
        for (int jr = 0; jr < 4; ++jr) {
            int srcl = (2 * (q & 1) + (jr >> 1)) * 16 + n15;
            unsigned v0 = (unsigned)__shfl((int)psrc[2 * ks2][jr & 1], srcl, 64);
            unsigned v1 = (unsigned)__shfl((int)psrc[2 * ks2 + 1][jr & 1], srcl, 64);
            tmp[jr] = (q >> 1) ? v1 : v0;
        }
        U4H8 pf;
        pf.u.x = tmp[0]; pf.u.y = tmp[1]; pf.u.z = tmp[2]; pf.u.w = tmp[3];
#pragma unroll
        for (int nt = 0; nt < 4; ++nt) {
            U4H8 wb;
            wb.u = *(const uint4*)(w2t + (size_t)(nt * 16 + n15) * 32 + ks2 * 16 + q * 4);
            acc2[nt] = __builtin_amdgcn_mfma_f32_16x16x32_f16(
                pf.h, wb.h, acc2[nt], 0, 0, 0);
        }
    }

    // ---- epilogue: xh += out (f16 residual), pairs via shfl_xor ----
    // acc2[nt][r] = out[node = base16+4q+r][feat = 16nt+n15]
#pragma unroll
    for (int nt = 0; nt < 4; ++nt) {
#pragma unroll
        for (int r = 0; r < 4; ++r) {
            int node = base16 + 4 * q + r;
            float vnew = 0.0f;
            if (node < NN) {
                unsigned pu = xh[((size_t)node << 5) + (unsigned)((nt * 16 + n15) >> 1)];
                half2_t hp = u2h(pu);
                float vold = (n15 & 1) ? (float)hp[1] : (float)hp[0];
                vnew = vold + acc2[nt][r];
            }
            float vpart = __shfl_xor(vnew, 1, 64);
            if ((n15 & 1) == 0) {
                unsigned pv = pk2(vnew, vpart);
                int pidx = nt * 8 + (n15 >> 1);
                MU[wid][(4 * q + r) * 33 + pidx] = pv;
                if (node < NN) xh[((size_t)node << 5) + pidx] = pv;
            }
        }
    }

    if (do_zero) {   // re-zero exactly the agg chunks this lane read
        if (nodeB < NN) {
            float4 z4; z4.x = z4.y = z4.z = z4.w = 0.0f;
            float4* ap = (float4*)(agg + ((size_t)nodeB << 6));
            ap[2*q] = z4; ap[2*q + 1] = z4;
            ap[8 + 2*q] = z4; ap[8 + 2*q + 1] = z4;
        }
    }

    if (do_head) {
        __syncthreads();   // MU visibility
        f32x4 acch[4];
#pragma unroll
        for (int mt = 0; mt < 4; ++mt)
            acch[mt] = *(const f32x4*)(ehb1 + mt * 16 + q * 4);
#pragma unroll
        for (int ks = 0; ks < 2; ++ks) {
            U4H8 bfk;
            bfk.u.x = MU[wid][n15 * 33 + ks * 16 + 4 * q + 0];
            bfk.u.y = MU[wid][n15 * 33 + ks * 16 + 4 * q + 1];
            bfk.u.z = MU[wid][n15 * 33 + ks * 16 + 4 * q + 2];
            bfk.u.w = MU[wid][n15 * 33 + ks * 16 + 4 * q + 3];
#pragma unroll
            for (int mt = 0; mt < 4; ++mt) {
                U4H8 af;
                af.u = *(const uint4*)(ehw1t + (size_t)(mt * 16 + n15) * 32 + ks * 16 + q * 4);
                acch[mt] = __builtin_amdgcn_mfma_f32_16x16x32_f16(
                    af.h, bfk.h, acch[mt], 0, 0, 0);
            }
        }
        f32x4 wv[4];
#pragma unroll
        for (int mt = 0; mt < 4; ++mt)
            wv[mt] = *(const f32x4*)(ehw2 + mt * 16 + q * 4);
        float e = 0.0f;
#pragma unroll
        for (int mt = 0; mt < 4; ++mt)
#pragma unroll
            for (int r = 0; r < 4; ++r)
                e = fmaf(silu_f(acch[mt][r]), wv[mt][r], e);
        e += __shfl_xor(e, 16, 64);
        e += __shfl_xor(e, 32, 64);
        if (q == 0) {
            int node = base16 + n15;
            if (node < NN) atomicAdd(&esum[batch[node]], e + ehb2[0]);
        }
        __syncthreads();
        if (tid < NGRAPH) {
            float v = esum[tid];
            if (v != 0.0f) atomicAdd(energy + tid, v);
        }
    }
}

extern "C" void kernel_launch(void* const* d_in, const int* in_sizes, int n_in,
                              void* d_out, int out_size, void* d_ws, size_t ws_size,
                              hipStream_t stream) {
    const int*   z       = (const int*)  d_in[0];
    const float* pos     = (const float*)d_in[1];
    const int*   eidx    = (const int*)  d_in[2];
    const int*   batch   = (const int*)  d_in[3];
    const float* embed   = (const float*)d_in[4];
    const float* msg_w1  = (const float*)d_in[5];
    const float* msg_b1  = (const float*)d_in[6];
    const float* msg_w2  = (const float*)d_in[7];
    const float* msg_b2  = (const float*)d_in[8];
    const float* upd_w1  = (const float*)d_in[9];
    const float* upd_b1  = (const float*)d_in[10];
    const float* upd_w2  = (const float*)d_in[11];
    const float* upd_b2  = (const float*)d_in[12];
    const float* eh_w1   = (const float*)d_in[13];
    const float* eh_b1   = (const float*)d_in[14];
    const float* eh_w2   = (const float*)d_in[15];
    const float* eh_b2   = (const float*)d_in[16];

    const int* erow = eidx;
    const int* ecol = eidx + EE;

    // ws layout (4-byte units); edgeS offset is 8B-aligned
    float*    agg    = (float*)d_ws;                      // NN*64
    unsigned* xh     = (unsigned*)(agg + (size_t)NN * HH);// NN*32
    int*      deg    = (int*)(xh + (size_t)NN * 32);      // NN
    int*      cursor = deg + NN;                          // NN
    int*      bsum   = cursor + NN;                       // 64 (bsum[63] = ticket)
    uint2*    edgeS  = (uint2*)(bsum + 64);               // EE uint2 (8B)
    unsigned* w1t    = (unsigned*)(edgeS + EE);           // NL*64*80
    unsigned* w2t    = w1t + NLAYER * 64 * 80;            // NL*64*32 (retired; hosts vbuf)
    unsigned* w1tu   = w2t + NLAYER * 64 * 32;            // NL*64*64
    unsigned* w2tu   = w1tu + NLAYER * 64 * 64;           // NL*64*32
    unsigned* ehw1t  = w2tu + NLAYER * 64 * 32;           // 64*32
    float*    vbuf   = (float*)w2t;                       // NL*64 (in w2t slot)
    float*    energy = (float*)d_out;

    (void)hipMemsetAsync(energy, 0, NGRAPH * sizeof(float), stream);
    // zero deg + cursor + bsum (incl. bsum[63] ticket) in one call
    (void)hipMemsetAsync(deg, 0, (2 * NN + 64) * sizeof(int), stream);

    // r28 pipeline: degcount -> scan -> fused{scatter | gather | prepack |
    // aggzero} -> layers.
    degcnt_k<<<EE / 256, 256, 0, stream>>>(ecol, deg);
    scan1_k<<<NBLK1, 1024, 0, stream>>>(deg, cursor, bsum);  // scan2 fused
    prep2_k<<<12612, 256, 0, stream>>>(
        erow, ecol, pos, cursor, bsum, edgeS,
        z, embed, xh,
        msg_w1, msg_w2, msg_b2, upd_w1, upd_w2, eh_w1,
        w1t, vbuf, w1tu, w2tu, ehw1t,
        (float4*)agg);

    for (int l = 0; l < NLAYER; ++l) {
        msg_k<<<EE / 256, 256, 0, stream>>>(   // r30: back to 64-edge windows
            edgeS, xh,
            w1t + (size_t)l * 64 * 80,
            msg_b1 + (size_t)l * HH,
            agg);
        upd_k<<<(NN + 63) / 64, 256, 0, stream>>>(
            xh, agg,
            w1tu + (size_t)l * 64 * 64,
            upd_b1 + (size_t)l * HH,
            vbuf + (size_t)l * 64,
            deg,
            w2tu + (size_t)l * 64 * 32,
            upd_b2 + (size_t)l * HH,
            ehw1t, eh_b1, eh_w2, eh_b2, batch, energy,
            (l == 0) ? 1 : 0,            // re-zero agg for next layer
            (l == NLAYER - 1) ? 1 : 0);  // fused head on last layer
    }
}

// Round 13
// 324.857 us; speedup vs baseline: 1.0411x; 1.0126x over previous
//
#include <hip/hip_runtime.h>
#include <math.h>

#define NN 50000
#define EE 800000
#define HH 64
#define NBASIS 8
#define NLAYER 2
#define NGRAPH 64
#define NBLK1 49  // ceil(NN/1024)

using half2_t = decltype(__builtin_amdgcn_cvt_pkrtz(0.0f, 0.0f));
typedef _Float16 f16x8 __attribute__((ext_vector_type(8)));
typedef float f32x4 __attribute__((ext_vector_type(4)));

union U4H8 { uint4 u; f16x8 h; };

// r27: fast silu — v_rcp_f32 instead of the ~12-instr exact-division
// sequence. rel err ~1ulp, far below the f16 rounding this path tolerates.
__device__ __forceinline__ float silu_f(float v) {
    return v * __builtin_amdgcn_rcpf(1.0f + __expf(-v));
}

__device__ __forceinline__ unsigned pk2(float a, float b) {
    union { half2_t h; unsigned u; } x;
    x.h = __builtin_amdgcn_cvt_pkrtz(a, b);
    return x.u;
}

__device__ __forceinline__ half2_t u2h(unsigned u) {
    union { unsigned u; half2_t h; } x; x.u = u; return x.h;
}

// r28: degree count split out (the only prep piece scan depends on).
__global__ __launch_bounds__(256) void degcnt_k(
    const int* __restrict__ ecol, int* __restrict__ deg)
{
    int e = blockIdx.x * 256 + threadIdx.x;   // grid = EE/256 exactly
    atomicAdd(&deg[ecol[e]], 1);
}

// r26: scan2 fused via last-block ticket (bsum[63] is the ticket counter,
// zeroed by the widened memset). Classic threadfence-reduction pattern.
__global__ __launch_bounds__(1024) void scan1_k(
    const int* __restrict__ deg, int* __restrict__ cursor,
    int* __restrict__ bsum)
{
    __shared__ int wsum[16];
    __shared__ int lastFlag;
    int t = threadIdx.x, lane = t & 63, wave = t >> 6;
    int i = blockIdx.x * 1024 + t;
    int v = (i < NN) ? deg[i] : 0;
    int s = v;
#pragma unroll
    for (int off = 1; off < 64; off <<= 1) {
        int tv = __shfl_up(s, off, 64);
        if (lane >= off) s += tv;
    }
    if (lane == 63) wsum[wave] = s;
    __syncthreads();
    if (wave == 0) {
        int ws = (lane < 16) ? wsum[lane] : 0;
        int ss = ws;
#pragma unroll
        for (int off = 1; off < 16; off <<= 1) {
            int tv = __shfl_up(ss, off, 64);
            if (lane >= off) ss += tv;
        }
        if (lane < 16) wsum[lane] = ss - ws;
    }
    __syncthreads();
    int excl = wsum[wave] + s - v;
    if (i < NN) cursor[i] = excl;     // block-local exclusive scan
    if (t == 1023) {
        bsum[blockIdx.x] = excl + v;
        __threadfence();              // release: bsum store visible
        lastFlag = (atomicAdd(&bsum[63], 1) == NBLK1 - 1);
    }
    __syncthreads();
    if (lastFlag != 0 && wave == 0) { // last block: fused scan2
        __threadfence();              // acquire: see all bsum stores
        int vv = (lane < NBLK1) ? bsum[lane] : 0;
        int ss = vv;
#pragma unroll
        for (int off = 1; off < 64; off <<= 1) {
            int tv = __shfl_up(ss, off, 64);
            if (lane >= off) ss += tv;
        }
        if (lane < NBLK1) bsum[lane] = ss - vv;
    }
}

// r28: fused prep2 — scatter (blocks 0..3124) + embed gather (3125..9374)
// + weight prepack (9375..9486) + agg zero (9487..12611). Scatter is
// latency-bound on random line evictions; co-residing with BW-bound blocks
// fills the stalls. r31: edgeS widened to uint4 {row<<16|col, d_bits,
// zr<<16|zc, 0} — same line count (16B in 64B line), enables msg_k's
// layer-0 L1-resident z-table gathers. xtab prepack added (100x32 pairs).
// W2-fold (r19) unchanged.
__global__ __launch_bounds__(256) void prep2_k(
    const int* __restrict__ erow, const int* __restrict__ ecol,
    const float* __restrict__ pos,
    int* __restrict__ cursor, const int* __restrict__ bsum,
    uint4* __restrict__ edgeS,
    const int* __restrict__ z, const float* __restrict__ embed,
    unsigned* __restrict__ xh,
    const float* __restrict__ msg_w1, const float* __restrict__ msg_w2,
    const float* __restrict__ msg_b2,
    const float* __restrict__ upd_w1, const float* __restrict__ upd_w2,
    const float* __restrict__ eh_w1,
    unsigned* __restrict__ w1t, float* __restrict__ vbuf,
    unsigned* __restrict__ w1tu, unsigned* __restrict__ w2tu,
    unsigned* __restrict__ ehw1t, unsigned* __restrict__ xtab,
    float4* __restrict__ agg4)
{
    int b = blockIdx.x;
    if (b < 3125) {                       // scatter: EE edges exactly
        int e = b * 256 + threadIdx.x;
        int c = ecol[e], r = erow[e];
        int slot = atomicAdd(&cursor[c], 1) + bsum[c >> 10];
        float dx = pos[3*r]   - pos[3*c];
        float dy = pos[3*r+1] - pos[3*c+1];
        float dz = pos[3*r+2] - pos[3*c+2];
        float d = sqrtf(dx*dx + dy*dy + dz*dz);
        uint4 v;
        v.x = ((unsigned)r << 16) | (unsigned)c;
        v.y = __float_as_uint(d);
        v.z = ((unsigned)z[r] << 16) | (unsigned)z[c];  // L2-hot 200KB
        v.w = 0;
        edgeS[slot] = v;
    } else if (b < 9375) {                // embed gather: NN*32 pairs
        int idx = (b - 3125) * 256 + threadIdx.x;  // < 1,600,000 always
        int n = idx >> 5;
        int p = idx & 31;
        const float2* er = (const float2*)(embed + ((size_t)z[n] << 6));
        float2 v = er[p];
        xh[idx] = pk2(v.x, v.y);
    } else if (b < 9487) {                // weight prepack, 28672 threads
        int idx = (b - 9375) * 256 + threadIdx.x;
        if (idx < 10240) {                    // msg w1t [l][f 64][kp 80]
            int l = idx / 5120, rem = idx % 5120;
            int f = rem / 80, kp = rem % 80;
            const float* w = msg_w1 + (size_t)l * 136 * 64;
            unsigned v = 0;
            if (kp < 68) v = pk2(w[(2*kp)*64 + f], w[(2*kp+1)*64 + f]);
            w1t[idx] = v;
        } else if (idx < 13440) {             // r31: xtab 100 rows x 32 pairs
            int j = idx - 10240;
            int zz = j >> 5, p = j & 31;
            const float2* er = (const float2*)(embed + ((size_t)zz << 6));
            float2 v = er[p];
            xtab[j] = pk2(v.x, v.y);
        } else if (idx < 14336) {
            // free slot (msg w2t retired by r19 W2-fold)
        } else if (idx < 22528) {             // upd w1tu [l][f 64][kp 64]
            int j = idx - 14336;
            int l = j / 4096, rem = j % 4096;
            int f = rem >> 6, kp = rem & 63;
            const float* w = upd_w1 + (size_t)l * 128 * 64;
            unsigned outv;
            if (kp < 32) {                    // x-half: passthrough
                outv = pk2(w[(2*kp)*64 + f], w[(2*kp+1)*64 + f]);
            } else {                          // agg-half: W2 @ W1u_agg
                const float* w2m = msg_w2 + (size_t)l * 64 * 64;
                int j0 = 2 * kp - 64;
                float v0 = 0.0f, v1 = 0.0f;
                for (int k = 0; k < 64; ++k) {
                    float wa = w[(64 + k) * 64 + f];
                    v0 += w2m[j0 * 64 + k]       * wa;
                    v1 += w2m[(j0 + 1) * 64 + k] * wa;
                }
                outv = pk2(v0, v1);
                if (kp == 63) {               // deg-bias vector vb
                    const float* b2m = msg_b2 + (size_t)l * 64;
                    float s = 0.0f;
                    for (int k = 0; k < 64; ++k)
                        s += b2m[k] * w[(64 + k) * 64 + f];
                    vbuf[l * 64 + f] = s;
                }
            }
            w1tu[j] = outv;
        } else if (idx < 26624) {             // upd w2tu [l][n 64][kp 32]
            int j = idx - 22528;
            int l = j / 2048, rem = j % 2048;
            int n = rem / 32, kp = rem % 32;
            const float* w = upd_w2 + (size_t)l * 64 * 64;
            w2tu[j] = pk2(w[(2*kp)*64 + n], w[(2*kp+1)*64 + n]);
        } else if (idx < 28672) {             // head ehw1t [f 64][kp 32]
            int j = idx - 26624;
            int f = j / 32, kp = j % 32;
            ehw1t[j] = pk2(eh_w1[(2*kp)*64 + f], eh_w1[(2*kp+1)*64 + f]);
        }
    } else {                              // agg zero: NN*16 float4
        int idx = (b - 9487) * 256 + threadIdx.x;
        if (idx < NN * 16) {
            float4 z4; z4.x = z4.y = z4.z = z4.w = 0.0f;
            agg4[idx] = z4;
        }
    }
}

// MFMA msg kernel: 256-thread blocks = 4 private waves x 64 sorted edges.
// r13 lockstep barrier; r18 early row gathers; r19 GEMM2 folded into upd;
// r24 transposed GEMM1 + in-register segmented reduce; r27 fast-rcp silu.
// OCCUPANCY LINE CLOSED (r25+r29): 64-edge window @ 4 waves/SIMD is the
// local optimum. r31: LAYER-0 Z-TABLE — x[n]=embed[z[n]] with only 100
// distinct z, so layer 0's random xh gathers (L2/L3, 6.4MB) become
// xtab gathers (12.8KB, L1-resident). use_tab swaps base+index only;
// values bit-identical. Layer 1 (use_tab=0) unchanged.
__global__ __launch_bounds__(256, 4) void msg_k(
    const uint4* __restrict__ edgeS,
    const unsigned* __restrict__ xh,
    const unsigned* __restrict__ xtab, int use_tab,
    const unsigned* __restrict__ w1t, const float* __restrict__ b1,
    float* __restrict__ agg)
{
    __shared__ unsigned earrT[4][4 * 64];   // [wid][p*64 + lane]
    __shared__ int ckey_s[4][64];

    const int wid  = threadIdx.x >> 6;
    const int lane = threadIdx.x & 63;
    const int q = lane >> 4, n15 = lane & 15;
    const size_t base = (size_t)blockIdx.x * 256 + wid * 64;

    uint4 ev = edgeS[base + lane];
    int myrow = (int)(ev.x >> 16);
    int mykey = (int)(ev.x & 0xffffu);
    ckey_s[wid][lane] = mykey;

    // gather source: layer 0 -> z-table (L1-hot), layer 1 -> xh
    const unsigned* xb = use_tab ? xtab : xh;
    int gc = use_tab ? (int)(ev.z & 0xffffu) : mykey;
    int gr = use_tab ? (int)(ev.z >> 16)     : myrow;

    // permuted edge slot: A-tile et, A-row n15 -> sorted offset oo0 + 4*et
    // (gives lane (q,*) the contiguous edges [16q, 16q+15] in its C regs)
    const int oo0 = 16 * (n15 >> 2) + (n15 & 3);

    int cn[4], rn[4];
#pragma unroll
    for (int et = 0; et < 4; ++et) {
        cn[et] = __shfl(gc, oo0 + 4 * et, 64);
        rn[et] = __shfl(gr, oo0 + 4 * et, 64);
    }

    // issue the random row gathers NOW; latency overlaps sinf phase
    U4H8 bfr[2][4];
#pragma unroll
    for (int et = 0; et < 4; ++et) {
        const uint4* rp = (const uint4*)(xb + ((size_t)rn[et] << 5));
        bfr[0][et].u = rp[q];
        bfr[1][et].u = rp[4 + q];
    }

    // ---- per-edge radial basis -> earrT (own edge at own position) ----
    {
        float d = __uint_as_float(ev.y);
        float env = 0.0f;
        if (d < 5.0f) {
            float cv = __cosf(d * 0.31415926535897932f);  // pi/(2*CUTOFF)
            env = cv * cv;
        }
        float scale = (d > 0.0f) ? (env * __builtin_amdgcn_rcpf(d)) : env;
        float ea[NBASIS];
#pragma unroll
        for (int k = 0; k < NBASIS; ++k)
            ea[k] = __sinf((float)(k + 1) * 0.62831853071795865f * d) * scale;
#pragma unroll
        for (int p = 0; p < 4; ++p)
            earrT[wid][p * 64 + lane] = pk2(ea[2*p], ea[2*p+1]);
    }
    // boundary bitmask: bit L set iff key[L] != key[L-1]
    int pkk = __shfl_up(mykey, 1, 64);
    unsigned long long bmask = __ballot(lane > 0 && mykey != pkk);
    __syncthreads();   // lockstep + earrT/ckey visibility

    // ---- GEMM1 (transposed): D[edge][feat] ----
    f32x4 acc1[4][4];   // [et][ft]
#pragma unroll
    for (int ft = 0; ft < 4; ++ft) {
        float bv = b1[ft * 16 + n15];
        f32x4 binit; binit[0] = bv; binit[1] = bv; binit[2] = bv; binit[3] = bv;
#pragma unroll
        for (int et = 0; et < 4; ++et) acc1[et][ft] = binit;
    }
#pragma unroll
    for (int ks = 0; ks < 5; ++ks) {
        U4H8 afrag[4];
#pragma unroll
        for (int et = 0; et < 4; ++et) {
            if (ks == 4) {
                int eB = oo0 + 4 * et;
                unsigned e0 = earrT[wid][0 * 64 + eB];
                unsigned e1 = earrT[wid][1 * 64 + eB];
                unsigned e2 = earrT[wid][2 * 64 + eB];
                unsigned e3 = earrT[wid][3 * 64 + eB];
                afrag[et].u.x = (q == 0) ? e0 : 0u;
                afrag[et].u.y = (q == 0) ? e1 : 0u;
                afrag[et].u.z = (q == 0) ? e2 : 0u;
                afrag[et].u.w = (q == 0) ? e3 : 0u;
            } else if (ks < 2) {
                afrag[et].u = ((const uint4*)(xb + ((size_t)cn[et] << 5)))[ks * 4 + q];
            } else {
                afrag[et] = bfr[ks - 2][et];
            }
        }
#pragma unroll
        for (int ft = 0; ft < 4; ++ft) {
            U4H8 wf;
            wf.u = *(const uint4*)(w1t + (size_t)(ft * 16 + n15) * 80 + ks * 16 + q * 4);
#pragma unroll
            for (int et = 0; et < 4; ++et)
                acc1[et][ft] = __builtin_amdgcn_mfma_f32_16x16x32_f16(
                    afrag[et].h, wf.h, acc1[et][ft], 0, 0, 0);
        }
    }

    // ---- in-register segmented reduce over contiguous edges [16q,16q+15].
    // value(i, ft) = silu(acc1[i>>2][ft][i&3]) = h[16q+i][16ft+n15].
    unsigned myb = (unsigned)((bmask >> (16 * q)) & 0xffffull);
    const bool bstart = (myb & 1u) != 0;    // boundary AT block start (q0: 0)
    float run[4], hs[4];
#pragma unroll
    for (int ft = 0; ft < 4; ++ft) run[ft] = silu_f(acc1[0][ft][0]);
    bool seenb = false; int fb = 0;
#pragma unroll
    for (int i = 1; i < 16; ++i) {
        float vv[4];
#pragma unroll
        for (int ft = 0; ft < 4; ++ft) vv[ft] = silu_f(acc1[i >> 2][ft][i & 3]);
        if ((myb >> i) & 1u) {
            if (!seenb) {
                seenb = true; fb = i;
#pragma unroll
                for (int ft = 0; ft < 4; ++ft) hs[ft] = run[ft];
            } else {
                // interior segment: sole writer, plain store (64B coalesced)
                int kk = ckey_s[wid][16 * q + i - 1];
                float* dst = agg + ((size_t)kk << 6) + n15;
#pragma unroll
                for (int ft = 0; ft < 4; ++ft) dst[16 * ft] = run[ft];
            }
#pragma unroll
            for (int ft = 0; ft < 4; ++ft) run[ft] = vv[ft];
        } else {
#pragma unroll
            for (int ft = 0; ft < 4; ++ft) run[ft] += vv[ft];
        }
    }

    // ---- stitch across q-lanes: segmented inclusive scan of tails ----
    float ct[4];
#pragma unroll
    for (int ft = 0; ft < 4; ++ft) ct[ft] = run[ft];
    int brk = (seenb || bstart) ? 1 : 0;
    {
        float cp[4]; int bp;
#pragma unroll
        for (int ft = 0; ft < 4; ++ft) cp[ft] = __shfl_up(ct[ft], 16, 64);
        bp = __shfl_up(brk, 16, 64);
        if (q >= 1) {
            if (!brk) {
#pragma unroll
                for (int ft = 0; ft < 4; ++ft) ct[ft] += cp[ft];
            }
            brk |= bp;
        }
#pragma unroll
        for (int ft = 0; ft < 4; ++ft) cp[ft] = __shfl_up(ct[ft], 32, 64);
        bp = __shfl_up(brk, 32, 64);
        if (q >= 2) {
            if (!brk) {
#pragma unroll
                for (int ft = 0; ft < 4; ++ft) ct[ft] += cp[ft];
            }
            brk |= bp;
        }
    }
    float carry[4];
#pragma unroll
    for (int ft = 0; ft < 4; ++ft) carry[ft] = __shfl_up(ct[ft], 16, 64);
    // headflag: no boundary in window bits 1..16q-1 -> chain reaches edge 0
    const bool headflag = (q == 0) ||
        ((bmask & (((unsigned long long)1 << (16 * q)) - 2)) == 0ull);

    if (q > 0 && bstart) {   // flush chain ending at edge 16q-1
        int kk = ckey_s[wid][16 * q - 1];
        float* dst = agg + ((size_t)kk << 6) + n15;
        if (headflag) {
#pragma unroll
            for (int ft = 0; ft < 4; ++ft) atomicAdd(dst + 16 * ft, carry[ft]);
        } else {
#pragma unroll
            for (int ft = 0; ft < 4; ++ft) dst[16 * ft] = carry[ft];
        }
    }
    if (seenb) {             // flush head segment [block start, fb-1]
        int kk = ckey_s[wid][16 * q + fb - 1];
        float* dst = agg + ((size_t)kk << 6) + n15;
        if (!bstart && q > 0) {
#pragma unroll
            for (int ft = 0; ft < 4; ++ft) hs[ft] += carry[ft];
        }
        if (headflag && !bstart) {
#pragma unroll
            for (int ft = 0; ft < 4; ++ft) atomicAdd(dst + 16 * ft, hs[ft]);
        } else {
#pragma unroll
            for (int ft = 0; ft < 4; ++ft) dst[16 * ft] = hs[ft];
        }
    }
    if (q == 3) {            // window tail, always atomic
        int kk = ckey_s[wid][63];
        float* dst = agg + ((size_t)kk << 6) + n15;
#pragma unroll
        for (int ft = 0; ft < 4; ++ft) atomicAdd(dst + 16 * ft, ct[ft]);
    }
}

// MFMA upd kernel: 16 nodes per wave, 256-thr blocks. Residual lives in xh
// (f16): epilogue reads old pair, adds, re-packs. Optional fused head and
// agg re-zero. r19+: w1t here carries the W2-folded agg-half; bias gains
// the per-node deg[n]*vb term (b2 of msg pushed through segment_sum).
__global__ __launch_bounds__(256) void upd_k(
    unsigned* __restrict__ xh,
    float* __restrict__ agg,
    const unsigned* __restrict__ w1t, const float* __restrict__ b1,
    const float* __restrict__ vb, const int* __restrict__ deg,
    const unsigned* __restrict__ w2t, const float* __restrict__ b2,
    const unsigned* __restrict__ ehw1t, const float* __restrict__ ehb1,
    const float* __restrict__ ehw2, const float* __restrict__ ehb2,
    const int* __restrict__ batch, float* __restrict__ energy,
    int do_zero, int do_head)
{
    __shared__ unsigned MU[4][16 * 33];   // per-wave f16-pair staging
    __shared__ float esum[NGRAPH];

    const int tid = threadIdx.x;
    const int wid = tid >> 6;
    const int lane = tid & 63;
    const int q = lane >> 4, n15 = lane & 15;
    const int base16 = blockIdx.x * 64 + wid * 16;   // wave's first node

    if (do_head) {
        if (tid < NGRAPH) esum[tid] = 0.0f;
        __syncthreads();
    }

    int nodeB = base16 + n15;
    int ncB = (nodeB < NN) ? nodeB : (NN - 1);

    // ---- GEMM1: H^T = W1T @ u_in^T, K=128, single node tile ----
    float degf = (float)deg[ncB];
    f32x4 acc1[4];
#pragma unroll
    for (int mt = 0; mt < 4; ++mt) {
        f32x4 bi = *(const f32x4*)(b1 + mt * 16 + q * 4);
        f32x4 vv = *(const f32x4*)(vb + mt * 16 + q * 4);
#pragma unroll
        for (int r = 0; r < 4; ++r) bi[r] = fmaf(degf, vv[r], bi[r]);
        acc1[mt] = bi;
    }
#pragma unroll
    for (int ks = 0; ks < 4; ++ks) {
        U4H8 bfk;
        if (ks < 2) {
            bfk.u = ((const uint4*)(xh + ((size_t)ncB << 5)))[ks * 4 + q];
        } else {
            const float4* ap = (const float4*)(agg + ((size_t)ncB << 6));
            int o = (ks - 2) * 8 + 2 * q;
            float4 a0 = ap[o], a1 = ap[o + 1];
            bfk.u.x = pk2(a0.x, a0.y); bfk.u.y = pk2(a0.z, a0.w);
            bfk.u.z = pk2(a1.x, a1.y); bfk.u.w = pk2(a1.z, a1.w);
        }
#pragma unroll
        for (int mt = 0; mt < 4; ++mt) {
            U4H8 af;
            af.u = *(const uint4*)(w1t + (size_t)(mt * 16 + n15) * 64 + ks * 16 + q * 4);
            acc1[mt] = __builtin_amdgcn_mfma_f32_16x16x32_f16(
                af.h, bfk.h, acc1[mt], 0, 0, 0);
        }
    }

    // ---- silu + pack ----
    unsigned psrc[4][2];
#pragma unroll
    for (int mt = 0; mt < 4; ++mt) {
        psrc[mt][0] = pk2(silu_f(acc1[mt][0]), silu_f(acc1[mt][1]));
        psrc[mt][1] = pk2(silu_f(acc1[mt][2]), silu_f(acc1[mt][3]));
    }

    // ---- GEMM2: out = P @ W2, K=64 ----
    f32x4 acc2[4];
#pragma unroll
    for (int nt = 0; nt < 4; ++nt) {
        float b2v = b2[nt * 16 + n15];
        acc2[nt][0] = b2v; acc2[nt][1] = b2v; acc2[nt][2] = b2v; acc2[nt][3] = b2v;
    }
#pragma unroll
    for (int ks2 = 0; ks2 < 2; ++ks2) {
        unsigned tmp[4];
#pragma unroll
        for (int jr = 0; jr < 4; ++jr) {
            int srcl = (2 * (q & 1) + (jr >> 1)) * 16 + n15;
            unsigned v0 = (unsigned)__shfl((int)psrc[2 * ks2][jr & 1], srcl, 64);
            unsigned v1 = (unsigned)__shfl((int)psrc[2 * ks2 + 1][jr & 1], srcl, 64);
            tmp[jr] = (q >> 1) ? v1 : v0;
        }
        U4H8 pf;
        pf.u.x = tmp[0]; pf.u.y = tmp[1]; pf.u.z = tmp[2]; pf.u.w = tmp[3];
#pragma unroll
        for (int nt = 0; nt < 4; ++nt) {
            U4H8 wb;
            wb.u = *(const uint4*)(w2t + (size_t)(nt * 16 + n15) * 32 + ks2 * 16 + q * 4);
            acc2[nt] = __builtin_amdgcn_mfma_f32_16x16x32_f16(
                pf.h, wb.h, acc2[nt], 0, 0, 0);
        }
    }

    // ---- epilogue: xh += out (f16 residual), pairs via shfl_xor ----
    // acc2[nt][r] = out[node = base16+4q+r][feat = 16nt+n15]
#pragma unroll
    for (int nt = 0; nt < 4; ++nt) {
#pragma unroll
        for (int r = 0; r < 4; ++r) {
            int node = base16 + 4 * q + r;
            float vnew = 0.0f;
            if (node < NN) {
                unsigned pu = xh[((size_t)node << 5) + (unsigned)((nt * 16 + n15) >> 1)];
                half2_t hp = u2h(pu);
                float vold = (n15 & 1) ? (float)hp[1] : (float)hp[0];
                vnew = vold + acc2[nt][r];
            }
            float vpart = __shfl_xor(vnew, 1, 64);
            if ((n15 & 1) == 0) {
                unsigned pv = pk2(vnew, vpart);
                int pidx = nt * 8 + (n15 >> 1);
                MU[wid][(4 * q + r) * 33 + pidx] = pv;
                if (node < NN) xh[((size_t)node << 5) + pidx] = pv;
            }
        }
    }

    if (do_zero) {   // re-zero exactly the agg chunks this lane read
        if (nodeB < NN) {
            float4 z4; z4.x = z4.y = z4.z = z4.w = 0.0f;
            float4* ap = (float4*)(agg + ((size_t)nodeB << 6));
            ap[2*q] = z4; ap[2*q + 1] = z4;
            ap[8 + 2*q] = z4; ap[8 + 2*q + 1] = z4;
        }
    }

    if (do_head) {
        __syncthreads();   // MU visibility
        f32x4 acch[4];
#pragma unroll
        for (int mt = 0; mt < 4; ++mt)
            acch[mt] = *(const f32x4*)(ehb1 + mt * 16 + q * 4);
#pragma unroll
        for (int ks = 0; ks < 2; ++ks) {
            U4H8 bfk;
            bfk.u.x = MU[wid][n15 * 33 + ks * 16 + 4 * q + 0];
            bfk.u.y = MU[wid][n15 * 33 + ks * 16 + 4 * q + 1];
            bfk.u.z = MU[wid][n15 * 33 + ks * 16 + 4 * q + 2];
            bfk.u.w = MU[wid][n15 * 33 + ks * 16 + 4 * q + 3];
#pragma unroll
            for (int mt = 0; mt < 4; ++mt) {
                U4H8 af;
                af.u = *(const uint4*)(ehw1t + (size_t)(mt * 16 + n15) * 32 + ks * 16 + q * 4);
                acch[mt] = __builtin_amdgcn_mfma_f32_16x16x32_f16(
                    af.h, bfk.h, acch[mt], 0, 0, 0);
            }
        }
        f32x4 wv[4];
#pragma unroll
        for (int mt = 0; mt < 4; ++mt)
            wv[mt] = *(const f32x4*)(ehw2 + mt * 16 + q * 4);
        float e = 0.0f;
#pragma unroll
        for (int mt = 0; mt < 4; ++mt)
#pragma unroll
            for (int r = 0; r < 4; ++r)
                e = fmaf(silu_f(acch[mt][r]), wv[mt][r], e);
        e += __shfl_xor(e, 16, 64);
        e += __shfl_xor(e, 32, 64);
        if (q == 0) {
            int node = base16 + n15;
            if (node < NN) atomicAdd(&esum[batch[node]], e + ehb2[0]);
        }
        __syncthreads();
        if (tid < NGRAPH) {
            float v = esum[tid];
            if (v != 0.0f) atomicAdd(energy + tid, v);
        }
    }
}

extern "C" void kernel_launch(void* const* d_in, const int* in_sizes, int n_in,
                              void* d_out, int out_size, void* d_ws, size_t ws_size,
                              hipStream_t stream) {
    const int*   z       = (const int*)  d_in[0];
    const float* pos     = (const float*)d_in[1];
    const int*   eidx    = (const int*)  d_in[2];
    const int*   batch   = (const int*)  d_in[3];
    const float* embed   = (const float*)d_in[4];
    const float* msg_w1  = (const float*)d_in[5];
    const float* msg_b1  = (const float*)d_in[6];
    const float* msg_w2  = (const float*)d_in[7];
    const float* msg_b2  = (const float*)d_in[8];
    const float* upd_w1  = (const float*)d_in[9];
    const float* upd_b1  = (const float*)d_in[10];
    const float* upd_w2  = (const float*)d_in[11];
    const float* upd_b2  = (const float*)d_in[12];
    const float* eh_w1   = (const float*)d_in[13];
    const float* eh_b1   = (const float*)d_in[14];
    const float* eh_w2   = (const float*)d_in[15];
    const float* eh_b2   = (const float*)d_in[16];

    const int* erow = eidx;
    const int* ecol = eidx + EE;

    // ws layout (4-byte units); edgeS offset is 16B-aligned
    // (prefix = NN*64 + NN*32 + NN + NN + 64 = 4,900,064 words, /4 exact)
    float*    agg    = (float*)d_ws;                      // NN*64
    unsigned* xh     = (unsigned*)(agg + (size_t)NN * HH);// NN*32
    int*      deg    = (int*)(xh + (size_t)NN * 32);      // NN
    int*      cursor = deg + NN;                          // NN
    int*      bsum   = cursor + NN;                       // 64 (bsum[63] = ticket)
    uint4*    edgeS  = (uint4*)(bsum + 64);               // EE uint4 (16B) — r31
    unsigned* w1t    = (unsigned*)(edgeS + EE);           // NL*64*80
    unsigned* w2t    = w1t + NLAYER * 64 * 80;            // NL*64*32 (retired; hosts vbuf)
    unsigned* w1tu   = w2t + NLAYER * 64 * 32;            // NL*64*64
    unsigned* w2tu   = w1tu + NLAYER * 64 * 64;           // NL*64*32
    unsigned* ehw1t  = w2tu + NLAYER * 64 * 32;           // 64*32
    unsigned* xtab   = ehw1t + 64 * 32;                   // 100*32 (r31 z-table)
    float*    vbuf   = (float*)w2t;                       // NL*64 (in w2t slot)
    float*    energy = (float*)d_out;

    (void)hipMemsetAsync(energy, 0, NGRAPH * sizeof(float), stream);
    // zero deg + cursor + bsum (incl. bsum[63] ticket) in one call
    (void)hipMemsetAsync(deg, 0, (2 * NN + 64) * sizeof(int), stream);

    // r28 pipeline: degcount -> scan -> fused{scatter | gather | prepack |
    // aggzero} -> layers.
    degcnt_k<<<EE / 256, 256, 0, stream>>>(ecol, deg);
    scan1_k<<<NBLK1, 1024, 0, stream>>>(deg, cursor, bsum);  // scan2 fused
    prep2_k<<<12612, 256, 0, stream>>>(
        erow, ecol, pos, cursor, bsum, edgeS,
        z, embed, xh,
        msg_w1, msg_w2, msg_b2, upd_w1, upd_w2, eh_w1,
        w1t, vbuf, w1tu, w2tu, ehw1t, xtab,
        (float4*)agg);

    for (int l = 0; l < NLAYER; ++l) {
        msg_k<<<EE / 256, 256, 0, stream>>>(
            edgeS, xh, xtab, (l == 0) ? 1 : 0,   // r31: layer-0 z-table
            w1t + (size_t)l * 64 * 80,
            msg_b1 + (size_t)l * HH,
            agg);
        upd_k<<<(NN + 63) / 64, 256, 0, stream>>>(
            xh, agg,
            w1tu + (size_t)l * 64 * 64,
            upd_b1 + (size_t)l * HH,
            vbuf + (size_t)l * 64,
            deg,
            w2tu + (size_t)l * 64 * 32,
            upd_b2 + (size_t)l * HH,
            ehw1t, eh_b1, eh_w2, eh_b2, batch, energy,
            (l == 0) ? 1 : 0,            // re-zero agg for next layer
            (l == NLAYER - 1) ? 1 : 0);  // fused head on last layer
    }
}